// Round 3
// baseline (608.433 us; speedup 1.0000x reference)
//
#include <hip/hip_runtime.h>
#include <hip/hip_bf16.h>
#include <math.h>

typedef __hip_bfloat16 bf16;

#define FEAT 128
#define NRBF 20
#define CUTOFF_F 5.0f

__device__ __forceinline__ float b2f(bf16 x) { return __bfloat162float(x); }
__device__ __forceinline__ bf16 f2b(float x) { return __float2bfloat16(x); }

template<int F32>
__device__ __forceinline__ float LD(const void* p, size_t i) {
    if (F32) return ((const float*)p)[i];
    return b2f(((const bf16*)p)[i]);
}
template<int F32>
__device__ __forceinline__ void ST(void* p, size_t i, float v) {
    if (F32) ((float*)p)[i] = v;
    else ((bf16*)p)[i] = f2b(v);
}

// nbrs accessors: is64==0 -> int32 pairs [dst,src]; is64==1 -> little-endian int64 pairs.
__device__ __forceinline__ int get_dst(const int* nb, int e, int is64) {
    return is64 ? nb[4 * e] : nb[2 * e];
}
__device__ __forceinline__ int get_src(const int* nb, int e, int is64) {
    return is64 ? nb[4 * e + 2] : nb[2 * e + 1];
}
__device__ __forceinline__ int clampi(int v, int n) {
    return v < 0 ? 0 : (v >= n ? n - 1 : v);
}

// ---------- init: zero counts + sniff dtypes ----------
// flags[0] = 1 if float inputs are f32 (else bf16); flags[1] = 1 if nbrs is int64.
__global__ void init_kernel(const void* __restrict__ s_ptr, const int* __restrict__ nbrs32,
                            int nE, int* __restrict__ flags, int* __restrict__ counts, int nN) {
    int t = blockIdx.x * blockDim.x + threadIdx.x;
    if (t < nN) counts[t] = 0;
    if (t == 0) {
        // float dtype sniff: for bf16 data, dword bits[14:7] are a bf16 exponent
        // field of an N(0,1) value -> concentrated near 126. For f32 data they are
        // mid-mantissa bits -> ~uniform.
        const unsigned* u = (const unsigned*)s_ptr;
        int hits = 0;
        for (int i = 0; i < 64; ++i) {
            unsigned ef = (u[i] >> 7) & 0xFF;
            hits += (ef >= 110 && ef <= 135) ? 1 : 0;
        }
        flags[0] = (hits < 32) ? 1 : 0;   // few hits -> not bf16 packing -> f32
        // nbrs width sniff: int64 little-endian => odd int32 words are 0.
        int lim = 2 * nE; if (lim > 128) lim = 128;
        int allz = 1;
        for (int i = 1; i < lim; i += 2) allz &= (nbrs32[i] == 0);
        flags[1] = allz;
    }
}

// ---------- CSR build ----------
__global__ void hist_kernel(const int* __restrict__ nbrs, const int* __restrict__ flags,
                            int* __restrict__ counts, int nE, int nN) {
    int e = blockIdx.x * blockDim.x + threadIdx.x;
    if (e < nE) {
        int d = clampi(get_dst(nbrs, e, flags[1]), nN);
        atomicAdd(&counts[d], 1);
    }
}

__global__ __launch_bounds__(1024) void scan_kernel(const int* __restrict__ counts,
        int* __restrict__ offsets, int* __restrict__ cursor, int nN) {
    __shared__ int part[1024];
    const int t = threadIdx.x;
    const int chunk = (nN + 1023) / 1024;
    const int base = t * chunk;
    int local[32];
    int sum = 0;
    for (int c = 0; c < chunk && c < 32; ++c) {
        int idx = base + c;
        int v = (idx < nN) ? counts[idx] : 0;
        local[c] = v;
        sum += v;
    }
    part[t] = sum;
    __syncthreads();
    for (int off = 1; off < 1024; off <<= 1) {
        int add = (t >= off) ? part[t - off] : 0;
        __syncthreads();
        part[t] += add;
        __syncthreads();
    }
    int run = part[t] - sum;
    for (int c = 0; c < chunk && c < 32; ++c) {
        int idx = base + c;
        if (idx < nN) { offsets[idx] = run; cursor[idx] = run; run += local[c]; }
    }
    if (t == 1023) offsets[nN] = part[1023];
}

__global__ void scatter_kernel(const int* __restrict__ nbrs, const int* __restrict__ flags,
                               int* __restrict__ cursor, int* __restrict__ edge_ids,
                               int nE, int nN) {
    int e = blockIdx.x * blockDim.x + threadIdx.x;
    if (e < nE) {
        int d = clampi(get_dst(nbrs, e, flags[1]), nN);
        int pos = atomicAdd(&cursor[d], 1);
        if (pos >= 0 && pos < nE) edge_ids[pos] = e;
    }
}

// ---------- fused node MLP: phi = silu(s@W1+b1)@W2 + b2 ----------
template<int F32, int PHIM>
__device__ void gemm_body(const void* __restrict__ s_j, const void* __restrict__ W1,
                          const void* __restrict__ b1, const void* __restrict__ W2,
                          const void* __restrict__ b2v, void* __restrict__ phi, int nN) {
    __shared__ float sl[8][FEAT];
    __shared__ float hl[8][FEAT];
    const int t = threadIdx.x;
    const int n0 = blockIdx.x * 8;
    for (int idx = t; idx < 8 * FEAT; idx += 384) {
        int n = idx >> 7, k = idx & 127;
        int row = n0 + n;
        sl[n][k] = (row < nN) ? LD<F32>(s_j, (size_t)row * FEAT + k) : 0.f;
    }
    __syncthreads();
    if (t < FEAT) {
        float acc[8] = {};
        #pragma unroll 4
        for (int k = 0; k < FEAT; ++k) {
            const float w = LD<F32>(W1, (size_t)k * FEAT + t);
            #pragma unroll
            for (int n = 0; n < 8; ++n) acc[n] = fmaf(sl[n][k], w, acc[n]);
        }
        const float bb = LD<F32>(b1, t);
        #pragma unroll
        for (int n = 0; n < 8; ++n) {
            float xv = acc[n] + bb;
            float sg = F32 ? (1.0f / (1.0f + expf(-xv))) : (1.0f / (1.0f + __expf(-xv)));
            hl[n][t] = xv * sg;
        }
    }
    __syncthreads();
    float acc[8] = {};
    #pragma unroll 4
    for (int k = 0; k < FEAT; ++k) {
        const float w = LD<F32>(W2, (size_t)k * 384 + t);
        #pragma unroll
        for (int n = 0; n < 8; ++n) acc[n] = fmaf(hl[n][k], w, acc[n]);
    }
    const float bb = LD<F32>(b2v, t);
    #pragma unroll
    for (int n = 0; n < 8; ++n) {
        int row = n0 + n;
        if (row < nN) ST<PHIM>(phi, (size_t)row * 384 + t, acc[n] + bb);
    }
}

template<int PHIM>
__global__ __launch_bounds__(384) void gemm_node_kernel(const void* s_j, const void* W1,
        const void* b1, const void* W2, const void* b2v, void* phi,
        const int* __restrict__ flags, int nN) {
    if (flags[0]) gemm_body<1, PHIM>(s_j, W1, b1, W2, b2v, phi, nN);
    else          gemm_body<0, PHIM>(s_j, W1, b1, W2, b2v, phi, nN);
}

// ---------- fused per-node message + reduce ----------
template<int F32, int PHIM>
__device__ void msg_body(const int* __restrict__ nbrs, int is64,
        const void* __restrict__ r_ij, const void* __restrict__ v_j,
        const void* __restrict__ Wd, const void* __restrict__ bd,
        const void* __restrict__ phi,
        const int* __restrict__ offsets, const int* __restrict__ edge_ids,
        void* __restrict__ out, int nE, int nN) {
    const int i = blockIdx.x;
    const int f = threadIdx.x;

    float wd0[NRBF], wd1[NRBF], wd2[NRBF];
    #pragma unroll
    for (int k = 0; k < NRBF; ++k) {
        wd0[k] = LD<F32>(Wd, (size_t)k * 384 + f);
        wd1[k] = LD<F32>(Wd, (size_t)k * 384 + FEAT + f);
        wd2[k] = LD<F32>(Wd, (size_t)k * 384 + 2 * FEAT + f);
    }
    const float bd0 = LD<F32>(bd, f);
    const float bd1 = LD<F32>(bd, FEAT + f);
    const float bd2 = LD<F32>(bd, 2 * FEAT + f);

    float ds = 0.f, dv0 = 0.f, dv1 = 0.f, dv2 = 0.f;

    int start = offsets[i];
    int end   = offsets[i + 1];
    if (start < 0) start = 0;
    if (end > nE) end = nE;
    const float kscale = 0.62831853071795864769f;  // pi / 5

    for (int p = start; p < end; ++p) {
        const int e = clampi(edge_ids[p], nE);
        const int j = clampi(get_src(nbrs, e, is64), nN);
        const float rx = LD<F32>(r_ij, (size_t)3 * e + 0);
        const float ry = LD<F32>(r_ij, (size_t)3 * e + 1);
        const float rz = LD<F32>(r_ij, (size_t)3 * e + 2);
        const float d2   = rx * rx + ry * ry + rz * rz + 3e-15f;
        const float invd = rsqrtf(d2);
        const float d    = d2 * invd;
        const float ux = rx * invd, uy = ry * invd, uz = rz * invd;
        const float x  = d * kscale;
        const float s1 = F32 ? sinf(x) : __sinf(x);
        const float c1 = F32 ? cosf(x) : __cosf(x);
        const float env = (d < CUTOFF_F) ? (0.5f * (c1 + 1.0f)) : 0.0f;
        const float tc = 2.0f * c1;
        float skm2 = 0.f, skm1 = s1;
        float t0 = s1 * wd0[0], t1 = s1 * wd1[0], t2 = s1 * wd2[0];
        #pragma unroll
        for (int k = 1; k < NRBF; ++k) {
            const float sk = fmaf(tc, skm1, -skm2);
            t0 = fmaf(sk, wd0[k], t0);
            t1 = fmaf(sk, wd1[k], t1);
            t2 = fmaf(sk, wd2[k], t2);
            skm2 = skm1; skm1 = sk;
        }
        const float w0 = fmaf(t0, invd, bd0) * env;
        const float w1 = fmaf(t1, invd, bd1) * env;
        const float w2 = fmaf(t2, invd, bd2) * env;

        const size_t pb = (size_t)j * 384;
        const float p0 = LD<PHIM>(phi, pb + f);
        const float p1 = LD<PHIM>(phi, pb + FEAT + f);
        const float p2 = LD<PHIM>(phi, pb + 2 * FEAT + f);
        const size_t vb = ((size_t)j * FEAT + f) * 3;
        const float vx = LD<F32>(v_j, vb + 0);
        const float vy = LD<F32>(v_j, vb + 1);
        const float vz = LD<F32>(v_j, vb + 2);

        const float i0 = w0 * p0;
        const float i1 = w1 * p1;
        const float i2 = w2 * p2;
        ds += i1;
        dv0 = fmaf(i2, ux, fmaf(i0, vx, dv0));
        dv1 = fmaf(i2, uy, fmaf(i0, vy, dv1));
        dv2 = fmaf(i2, uz, fmaf(i0, vz, dv2));
    }

    ST<F32>(out, (size_t)i * FEAT + f, ds);
    const size_t ob = (size_t)nN * FEAT + ((size_t)i * FEAT + f) * 3;
    ST<F32>(out, ob + 0, dv0);
    ST<F32>(out, ob + 1, dv1);
    ST<F32>(out, ob + 2, dv2);
}

template<int PHIM>
__global__ __launch_bounds__(128) void msg_kernel(const int* nbrs,
        const void* r_ij, const void* v_j, const void* Wd, const void* bd,
        const void* phi, const int* __restrict__ flags,
        const int* offsets, const int* edge_ids, void* out, int nE, int nN) {
    if (flags[0]) msg_body<1, PHIM>(nbrs, flags[1], r_ij, v_j, Wd, bd, phi, offsets, edge_ids, out, nE, nN);
    else          msg_body<0, PHIM>(nbrs, flags[1], r_ij, v_j, Wd, bd, phi, offsets, edge_ids, out, nE, nN);
}

extern "C" void kernel_launch(void* const* d_in, const int* in_sizes, int n_in,
                              void* d_out, int out_size, void* d_ws, size_t ws_size,
                              hipStream_t stream) {
    const void* s_j  = d_in[0];
    const void* v_j  = d_in[1];
    const void* r_ij = d_in[2];
    const int*  nbrs = (const int*)d_in[3];
    const void* W1   = d_in[4];
    const void* b1   = d_in[5];
    const void* W2   = d_in[6];
    const void* b2   = d_in[7];
    const void* Wd   = d_in[8];
    const void* bd   = d_in[9];

    const int nN = out_size / (4 * FEAT);   // 20000
    const int nE = in_sizes[2] / 3;         // 640000

    // workspace: flags | counts | offsets | cursor | edge_ids | phi
    char* ws = (char*)d_ws;
    size_t off = 0;
    int* flags = (int*)(ws + off);    off += 256;
    int* counts = (int*)(ws + off);   off += ((size_t)nN * 4 + 255) & ~(size_t)255;
    int* offsets = (int*)(ws + off);  off += (((size_t)nN + 1) * 4 + 255) & ~(size_t)255;
    int* cursor = (int*)(ws + off);   off += ((size_t)nN * 4 + 255) & ~(size_t)255;
    int* edge_ids = (int*)(ws + off); off += ((size_t)nE * 4 + 255) & ~(size_t)255;
    void* phi = (void*)(ws + off);
    const size_t phi_f32_bytes = (size_t)nN * 384 * 4;
    const int phim = (ws_size >= off + phi_f32_bytes) ? 1 : 0;  // f32 phi if it fits

    init_kernel<<<(nN + 255) / 256, 256, 0, stream>>>(s_j, nbrs, nE, flags, counts, nN);
    if (phim)
        gemm_node_kernel<1><<<(nN + 7) / 8, 384, 0, stream>>>(s_j, W1, b1, W2, b2, phi, flags, nN);
    else
        gemm_node_kernel<0><<<(nN + 7) / 8, 384, 0, stream>>>(s_j, W1, b1, W2, b2, phi, flags, nN);
    hist_kernel<<<(nE + 255) / 256, 256, 0, stream>>>(nbrs, flags, counts, nE, nN);
    scan_kernel<<<1, 1024, 0, stream>>>(counts, offsets, cursor, nN);
    scatter_kernel<<<(nE + 255) / 256, 256, 0, stream>>>(nbrs, flags, cursor, edge_ids, nE, nN);
    if (phim)
        msg_kernel<1><<<nN, 128, 0, stream>>>(nbrs, r_ij, v_j, Wd, bd, phi, flags,
                                              offsets, edge_ids, d_out, nE, nN);
    else
        msg_kernel<0><<<nN, 128, 0, stream>>>(nbrs, r_ij, v_j, Wd, bd, phi, flags,
                                              offsets, edge_ids, d_out, nE, nN);
}

// Round 4
// 596.243 us; speedup vs baseline: 1.0204x; 1.0204x over previous
//
#include <hip/hip_runtime.h>
#include <hip/hip_bf16.h>
#include <math.h>

typedef __hip_bfloat16 bf16;

#define FEAT 128
#define NRBF 20
#define CUTOFF_F 5.0f
#define KSCALE 0.62831853071795864769f  // pi / 5

__device__ __forceinline__ float b2f(bf16 x) { return __bfloat162float(x); }
__device__ __forceinline__ bf16 f2b(float x) { return __float2bfloat16(x); }

template<int F32>
__device__ __forceinline__ float LD(const void* p, size_t i) {
    if (F32) return ((const float*)p)[i];
    return b2f(((const bf16*)p)[i]);
}
template<int F32>
__device__ __forceinline__ void ST(void* p, size_t i, float v) {
    if (F32) ((float*)p)[i] = v;
    else ((bf16*)p)[i] = f2b(v);
}

__device__ __forceinline__ int get_dst(const int* nb, int e, int is64) {
    return is64 ? nb[4 * e] : nb[2 * e];
}
__device__ __forceinline__ int get_src(const int* nb, int e, int is64) {
    return is64 ? nb[4 * e + 2] : nb[2 * e + 1];
}
__device__ __forceinline__ int clampi(int v, int n) {
    return v < 0 ? 0 : (v >= n ? n - 1 : v);
}

// ---------- init: zero counts + sniff dtypes ----------
// flags[0] = 1 if float inputs are f32 (else bf16); flags[1] = 1 if nbrs is int64.
__global__ void init_kernel(const void* __restrict__ s_ptr, const int* __restrict__ nbrs32,
                            int nE, int* __restrict__ flags, int* __restrict__ counts, int nN) {
    int t = blockIdx.x * blockDim.x + threadIdx.x;
    if (t < nN) counts[t] = 0;
    if (t == 0) {
        const unsigned* u = (const unsigned*)s_ptr;
        int hits = 0;
        for (int i = 0; i < 64; ++i) {
            unsigned ef = (u[i] >> 7) & 0xFF;
            hits += (ef >= 110 && ef <= 135) ? 1 : 0;
        }
        flags[0] = (hits < 32) ? 1 : 0;
        int lim = 2 * nE; if (lim > 128) lim = 128;
        int allz = 1;
        for (int i = 1; i < lim; i += 2) allz &= (nbrs32[i] == 0);
        flags[1] = allz;
    }
}

// ---------- CSR build ----------
__global__ void hist_kernel(const int* __restrict__ nbrs, const int* __restrict__ flags,
                            int* __restrict__ counts, int nE, int nN) {
    int e = blockIdx.x * blockDim.x + threadIdx.x;
    if (e < nE) {
        int d = clampi(get_dst(nbrs, e, flags[1]), nN);
        atomicAdd(&counts[d], 1);
    }
}

__global__ __launch_bounds__(1024) void scan_kernel(const int* __restrict__ counts,
        int* __restrict__ offsets, int* __restrict__ cursor, int nN) {
    __shared__ int part[1024];
    const int t = threadIdx.x;
    const int chunk = (nN + 1023) / 1024;
    const int base = t * chunk;
    int local[32];
    int sum = 0;
    for (int c = 0; c < chunk && c < 32; ++c) {
        int idx = base + c;
        int v = (idx < nN) ? counts[idx] : 0;
        local[c] = v;
        sum += v;
    }
    part[t] = sum;
    __syncthreads();
    for (int off = 1; off < 1024; off <<= 1) {
        int add = (t >= off) ? part[t - off] : 0;
        __syncthreads();
        part[t] += add;
        __syncthreads();
    }
    int run = part[t] - sum;
    for (int c = 0; c < chunk && c < 32; ++c) {
        int idx = base + c;
        if (idx < nN) { offsets[idx] = run; cursor[idx] = run; run += local[c]; }
    }
    if (t == 1023) offsets[nN] = part[1023];
}

__global__ void scatter_kernel(const int* __restrict__ nbrs, const int* __restrict__ flags,
                               int* __restrict__ cursor, int* __restrict__ edge_ids,
                               int nE, int nN) {
    int e = blockIdx.x * blockDim.x + threadIdx.x;
    if (e < nE) {
        int d = clampi(get_dst(nbrs, e, flags[1]), nN);
        int pos = atomicAdd(&cursor[d], 1);
        if (pos >= 0 && pos < nE) edge_ids[pos] = e;
    }
}

// ---------- per-edge precompute: g_k = sin(k*x)*invd*env, unit, env ----------
// record: 24 values per edge: g[0..19], ux, uy, uz, env
template<int F32, int GM>   // GM: 2 = f32 record, 1 = bf16 record
__global__ __launch_bounds__(256) void pre_kernel(const void* __restrict__ r_ij,
        void* __restrict__ gbuf, const int* __restrict__ flags, int nE) {
    if (flags[0] != F32) return;
    int e = blockIdx.x * blockDim.x + threadIdx.x;
    if (e >= nE) return;
    const float rx = LD<F32>(r_ij, (size_t)3 * e + 0);
    const float ry = LD<F32>(r_ij, (size_t)3 * e + 1);
    const float rz = LD<F32>(r_ij, (size_t)3 * e + 2);
    const float d2   = rx * rx + ry * ry + rz * rz + 3e-15f;
    const float invd = rsqrtf(d2);
    const float d    = d2 * invd;
    const float x  = d * KSCALE;
    const float s1 = F32 ? sinf(x) : __sinf(x);
    const float c1 = F32 ? cosf(x) : __cosf(x);
    const float env = (d < CUTOFF_F) ? (0.5f * (c1 + 1.0f)) : 0.0f;
    const float scale = invd * env;
    float rec[24];
    const float tc = 2.0f * c1;
    float skm2 = 0.f, skm1 = s1;
    rec[0] = s1 * scale;
    #pragma unroll
    for (int k = 1; k < NRBF; ++k) {
        const float sk = fmaf(tc, skm1, -skm2);
        rec[k] = sk * scale;
        skm2 = skm1; skm1 = sk;
    }
    rec[20] = rx * invd; rec[21] = ry * invd; rec[22] = rz * invd; rec[23] = env;
    if (GM == 2) {
        float* dst = (float*)gbuf + (size_t)24 * e;
        #pragma unroll
        for (int i = 0; i < 24; ++i) dst[i] = rec[i];
    } else {
        bf16* dst = (bf16*)gbuf + (size_t)24 * e;
        #pragma unroll
        for (int i = 0; i < 24; ++i) dst[i] = f2b(rec[i]);
    }
}

// ---------- fused node MLP: phi = silu(s@W1+b1)@W2 + b2 (phi stored bf16) ----------
template<int F32>
__device__ void gemm_body(const void* __restrict__ s_j, const void* __restrict__ W1,
                          const void* __restrict__ b1, const void* __restrict__ W2,
                          const void* __restrict__ b2v, bf16* __restrict__ phi, int nN) {
    __shared__ float sl[8][FEAT];
    __shared__ float hl[8][FEAT];
    const int t = threadIdx.x;
    const int n0 = blockIdx.x * 8;
    for (int idx = t; idx < 8 * FEAT; idx += 384) {
        int n = idx >> 7, k = idx & 127;
        int row = n0 + n;
        sl[n][k] = (row < nN) ? LD<F32>(s_j, (size_t)row * FEAT + k) : 0.f;
    }
    __syncthreads();
    // phase 1 balanced over all 384 threads: 1024 outputs
    for (int idx = t; idx < 8 * FEAT; idx += 384) {
        int n = idx >> 7, f = idx & 127;
        float a = 0.f;
        #pragma unroll 4
        for (int k = 0; k < FEAT; ++k) a = fmaf(sl[n][k], LD<F32>(W1, (size_t)k * FEAT + f), a);
        a += LD<F32>(b1, f);
        float sg = F32 ? (1.0f / (1.0f + expf(-a))) : (1.0f / (1.0f + __expf(-a)));
        hl[n][f] = a * sg;
    }
    __syncthreads();
    float acc[8] = {};
    #pragma unroll 4
    for (int k = 0; k < FEAT; ++k) {
        const float w = LD<F32>(W2, (size_t)k * 384 + t);
        #pragma unroll
        for (int n = 0; n < 8; ++n) acc[n] = fmaf(hl[n][k], w, acc[n]);
    }
    const float bb = LD<F32>(b2v, t);
    #pragma unroll
    for (int n = 0; n < 8; ++n) {
        int row = n0 + n;
        if (row < nN) phi[(size_t)row * 384 + t] = f2b(acc[n] + bb);
    }
}

__global__ __launch_bounds__(384) void gemm_node_kernel(const void* s_j, const void* W1,
        const void* b1, const void* W2, const void* b2v, bf16* phi,
        const int* __restrict__ flags, int nN) {
    if (flags[0]) gemm_body<1>(s_j, W1, b1, W2, b2v, phi, nN);
    else          gemm_body<0>(s_j, W1, b1, W2, b2v, phi, nN);
}

// ---------- fused per-node message + reduce ----------
// GM: 2 = f32 g-record, 1 = bf16 g-record, 0 = inline recompute
template<int F32, int GM>
__global__ __launch_bounds__(128, 2) void msg_kernel(
        const int* __restrict__ nbrs, const void* __restrict__ r_ij,
        const void* __restrict__ v_j, const void* __restrict__ Wd,
        const void* __restrict__ bd, const bf16* __restrict__ phi,
        const void* __restrict__ gbuf, const int* __restrict__ flags,
        const int* __restrict__ offsets, const int* __restrict__ edge_ids,
        void* __restrict__ out, int nE, int nN) {
    if (flags[0] != F32) return;
    const int i = blockIdx.x;
    const int f = threadIdx.x;
    const int is64 = flags[1];

    float wd0[NRBF], wd1[NRBF], wd2[NRBF];
    #pragma unroll
    for (int k = 0; k < NRBF; ++k) {
        wd0[k] = LD<F32>(Wd, (size_t)k * 384 + f);
        wd1[k] = LD<F32>(Wd, (size_t)k * 384 + FEAT + f);
        wd2[k] = LD<F32>(Wd, (size_t)k * 384 + 2 * FEAT + f);
    }
    const float bd0 = LD<F32>(bd, f);
    const float bd1 = LD<F32>(bd, FEAT + f);
    const float bd2 = LD<F32>(bd, 2 * FEAT + f);

    float ds = 0.f, dv0 = 0.f, dv1 = 0.f, dv2 = 0.f;

    int start = offsets[i];
    int end   = offsets[i + 1];
    if (start < 0) start = 0;
    if (end > nE) end = nE;

    for (int p = start; p < end; ++p) {
        const int e = __builtin_amdgcn_readfirstlane(clampi(edge_ids[p], nE));
        const int j = __builtin_amdgcn_readfirstlane(clampi(get_src(nbrs, e, is64), nN));

        float gk[24];
        if (GM == 2) {
            const float* g = (const float*)gbuf + (size_t)24 * e;
            #pragma unroll
            for (int q = 0; q < 24; ++q) gk[q] = g[q];
        } else if (GM == 1) {
            const bf16* g = (const bf16*)gbuf + (size_t)24 * e;
            #pragma unroll
            for (int q = 0; q < 24; ++q) gk[q] = b2f(g[q]);
        } else {
            const float rx = LD<F32>(r_ij, (size_t)3 * e + 0);
            const float ry = LD<F32>(r_ij, (size_t)3 * e + 1);
            const float rz = LD<F32>(r_ij, (size_t)3 * e + 2);
            const float d2   = rx * rx + ry * ry + rz * rz + 3e-15f;
            const float invd = rsqrtf(d2);
            const float d    = d2 * invd;
            const float x  = d * KSCALE;
            const float s1 = F32 ? sinf(x) : __sinf(x);
            const float c1 = F32 ? cosf(x) : __cosf(x);
            const float env = (d < CUTOFF_F) ? (0.5f * (c1 + 1.0f)) : 0.0f;
            const float scale = invd * env;
            const float tc = 2.0f * c1;
            float skm2 = 0.f, skm1 = s1;
            gk[0] = s1 * scale;
            #pragma unroll
            for (int k = 1; k < NRBF; ++k) {
                const float sk = fmaf(tc, skm1, -skm2);
                gk[k] = sk * scale;
                skm2 = skm1; skm1 = sk;
            }
            gk[20] = rx * invd; gk[21] = ry * invd; gk[22] = rz * invd; gk[23] = env;
        }

        float t0 = 0.f, t1 = 0.f, t2 = 0.f;
        #pragma unroll
        for (int k = 0; k < NRBF; ++k) {
            t0 = fmaf(gk[k], wd0[k], t0);
            t1 = fmaf(gk[k], wd1[k], t1);
            t2 = fmaf(gk[k], wd2[k], t2);
        }
        const float env = gk[23];
        const float w0 = fmaf(bd0, env, t0);
        const float w1 = fmaf(bd1, env, t1);
        const float w2 = fmaf(bd2, env, t2);

        const size_t pb = (size_t)j * 384;
        const float p0 = b2f(phi[pb + f]);
        const float p1 = b2f(phi[pb + FEAT + f]);
        const float p2 = b2f(phi[pb + 2 * FEAT + f]);
        const size_t vb = ((size_t)j * FEAT + f) * 3;
        const float vx = LD<F32>(v_j, vb + 0);
        const float vy = LD<F32>(v_j, vb + 1);
        const float vz = LD<F32>(v_j, vb + 2);

        const float i0 = w0 * p0;
        const float i1 = w1 * p1;
        const float i2 = w2 * p2;
        ds += i1;
        dv0 = fmaf(i2, gk[20], fmaf(i0, vx, dv0));
        dv1 = fmaf(i2, gk[21], fmaf(i0, vy, dv1));
        dv2 = fmaf(i2, gk[22], fmaf(i0, vz, dv2));
    }

    ST<F32>(out, (size_t)i * FEAT + f, ds);
    const size_t ob = (size_t)nN * FEAT + ((size_t)i * FEAT + f) * 3;
    ST<F32>(out, ob + 0, dv0);
    ST<F32>(out, ob + 1, dv1);
    ST<F32>(out, ob + 2, dv2);
}

extern "C" void kernel_launch(void* const* d_in, const int* in_sizes, int n_in,
                              void* d_out, int out_size, void* d_ws, size_t ws_size,
                              hipStream_t stream) {
    const void* s_j  = d_in[0];
    const void* v_j  = d_in[1];
    const void* r_ij = d_in[2];
    const int*  nbrs = (const int*)d_in[3];
    const void* W1   = d_in[4];
    const void* b1   = d_in[5];
    const void* W2   = d_in[6];
    const void* b2   = d_in[7];
    const void* Wd   = d_in[8];
    const void* bd   = d_in[9];

    const int nN = out_size / (4 * FEAT);   // 20000
    const int nE = in_sizes[2] / 3;         // 640000

    // workspace: flags | counts | offsets | cursor | edge_ids | gbuf | phi(bf16)
    char* ws = (char*)d_ws;
    size_t off = 0;
    int* flags = (int*)(ws + off);    off += 256;
    int* counts = (int*)(ws + off);   off += ((size_t)nN * 4 + 255) & ~(size_t)255;
    int* offsets = (int*)(ws + off);  off += (((size_t)nN + 1) * 4 + 255) & ~(size_t)255;
    int* cursor = (int*)(ws + off);   off += ((size_t)nN * 4 + 255) & ~(size_t)255;
    int* edge_ids = (int*)(ws + off); off += ((size_t)nE * 4 + 255) & ~(size_t)255;

    const size_t phi_bytes = (size_t)nN * 384 * sizeof(bf16);
    const size_t g32_bytes = (size_t)nE * 24 * 4;
    const size_t g16_bytes = (size_t)nE * 24 * 2;
    int GM;
    size_t g_bytes;
    if (ws_size >= off + g32_bytes + phi_bytes)      { GM = 2; g_bytes = g32_bytes; }
    else if (ws_size >= off + g16_bytes + phi_bytes) { GM = 1; g_bytes = g16_bytes; }
    else                                             { GM = 0; g_bytes = 0; }
    void* gbuf = (void*)(ws + off);   off += (g_bytes + 255) & ~(size_t)255;
    bf16* phi = (bf16*)(ws + off);

    init_kernel<<<(nN + 255) / 256, 256, 0, stream>>>(s_j, nbrs, nE, flags, counts, nN);

    const int preg = (nE + 255) / 256;
    if (GM == 2) {
        pre_kernel<0, 2><<<preg, 256, 0, stream>>>(r_ij, gbuf, flags, nE);
        pre_kernel<1, 2><<<preg, 256, 0, stream>>>(r_ij, gbuf, flags, nE);
    } else if (GM == 1) {
        pre_kernel<0, 1><<<preg, 256, 0, stream>>>(r_ij, gbuf, flags, nE);
        pre_kernel<1, 1><<<preg, 256, 0, stream>>>(r_ij, gbuf, flags, nE);
    }

    gemm_node_kernel<<<(nN + 7) / 8, 384, 0, stream>>>(s_j, W1, b1, W2, b2, phi, flags, nN);
    hist_kernel<<<(nE + 255) / 256, 256, 0, stream>>>(nbrs, flags, counts, nE, nN);
    scan_kernel<<<1, 1024, 0, stream>>>(counts, offsets, cursor, nN);
    scatter_kernel<<<(nE + 255) / 256, 256, 0, stream>>>(nbrs, flags, cursor, edge_ids, nE, nN);

    if (GM == 2) {
        msg_kernel<0, 2><<<nN, 128, 0, stream>>>(nbrs, r_ij, v_j, Wd, bd, phi, gbuf, flags, offsets, edge_ids, d_out, nE, nN);
        msg_kernel<1, 2><<<nN, 128, 0, stream>>>(nbrs, r_ij, v_j, Wd, bd, phi, gbuf, flags, offsets, edge_ids, d_out, nE, nN);
    } else if (GM == 1) {
        msg_kernel<0, 1><<<nN, 128, 0, stream>>>(nbrs, r_ij, v_j, Wd, bd, phi, gbuf, flags, offsets, edge_ids, d_out, nE, nN);
        msg_kernel<1, 1><<<nN, 128, 0, stream>>>(nbrs, r_ij, v_j, Wd, bd, phi, gbuf, flags, offsets, edge_ids, d_out, nE, nN);
    } else {
        msg_kernel<0, 0><<<nN, 128, 0, stream>>>(nbrs, r_ij, v_j, Wd, bd, phi, gbuf, flags, offsets, edge_ids, d_out, nE, nN);
        msg_kernel<1, 0><<<nN, 128, 0, stream>>>(nbrs, r_ij, v_j, Wd, bd, phi, gbuf, flags, offsets, edge_ids, d_out, nE, nN);
    }
}